// Round 4
// baseline (1186.342 us; speedup 1.0000x reference)
//
#include <hip/hip_runtime.h>
#include <math.h>

#define NEGINF (-INFINITY)
#define SENT 999   // "dead / no entry" sentinel (> any row/col index)

// Parallel greedy hard-permutation via iterated locally-dominant matching.
// One wave (64 lanes) per batch. Lane l owns rows {64j+l} and cols {64j+l}.
// Row cache: (max over live cols, argcol). Col cache: (max over live rows, argrow).
// Each round: rescan stale caches (lockstep, pipelined), accept all mutual
// argmax pairs (== sequential greedy's picks under order (value, lower flat)),
// kill their rows/cols, repeat until 256 matched.
__global__ __launch_bounds__(64, 1) void greedy_perm_kernel(
        const float* __restrict__ soft, float* __restrict__ out) {
    const int lane = threadIdx.x;
    const size_t base = (size_t)blockIdx.x << 16;   // b * 256 * 256
    const float* sc = soft + base;
    float* ob = out + base;

    __shared__ int lds_colarg[256];                 // col c -> argrow (SENT if dead)
    __shared__ unsigned long long lds_rowdead[4], lds_coldead[4];

    if (lane < 4) { lds_rowdead[lane] = 0ull; lds_coldead[lane] = 0ull; }

    // fused zero-fill of this batch's output slice (lane writes its 4 owned rows;
    // the later 1.0 store to row r is issued by the SAME lane -> program order).
    const float4 zero4 = make_float4(0.f, 0.f, 0.f, 0.f);
    for (int k = 0; k < 64; ++k) {
#pragma unroll
        for (int j = 0; j < 4; ++j)
            ((float4*)(ob + (size_t)(j * 64 + lane) * 256))[k] = zero4;
    }

    float rv[4]; int rc[4];   // row caches (rows 64j+lane)
    float cv[4]; int cr[4];   // col caches (cols 64j+lane)
#pragma unroll
    for (int j = 0; j < 4; ++j) { rv[j] = NEGINF; rc[j] = 0; cv[j] = NEGINF; cr[j] = 0; }
    unsigned rdirty = 0xFu, cdirty = 0xFu;
    unsigned long long rowdead[4] = {0, 0, 0, 0}, coldead[4] = {0, 0, 0, 0};

    int matched = 0;
    __syncthreads();   // LDS masks initialized

    for (int round = 0; round < 300 && matched < 256; ++round) {
        // ---- row rescans: private lockstep, lane streams its own dirty rows ----
        if (__ballot(rdirty != 0u)) {
            float bv[4]; int bc[4];
#pragma unroll
            for (int j = 0; j < 4; ++j) { bv[j] = NEGINF; bc[j] = SENT; }
            for (int k = 0; k < 64; ++k) {
                // which of cols 4k..4k+3 are dead (wave-uniform nibble)
                const unsigned nib = (unsigned)(coldead[k >> 4] >> ((k & 15) * 4)) & 15u;
#pragma unroll
                for (int j = 0; j < 4; ++j) {
                    if (rdirty & (1u << j)) {
                        float4 w = ((const float4*)(sc + (size_t)(j * 64 + lane) * 256))[k];
                        float wx = (nib & 1u) ? NEGINF : w.x;
                        float wy = (nib & 2u) ? NEGINF : w.y;
                        float wz = (nib & 4u) ? NEGINF : w.z;
                        float ww = (nib & 8u) ? NEGINF : w.w;
                        if (wx > bv[j]) { bv[j] = wx; bc[j] = 4 * k + 0; }
                        if (wy > bv[j]) { bv[j] = wy; bc[j] = 4 * k + 1; }
                        if (wz > bv[j]) { bv[j] = wz; bc[j] = 4 * k + 2; }
                        if (ww > bv[j]) { bv[j] = ww; bc[j] = 4 * k + 3; }
                    }
                }
            }
#pragma unroll
            for (int j = 0; j < 4; ++j)
                if (rdirty & (1u << j)) { rv[j] = bv[j]; rc[j] = bc[j]; }
            rdirty = 0u;
        }

        // ---- col rescans: lockstep over rows, coalesced (lane reads col 64j+lane) ----
        if (__ballot(cdirty != 0u)) {
            float bv[4]; int br[4];
#pragma unroll
            for (int j = 0; j < 4; ++j) { bv[j] = NEGINF; br[j] = SENT; }
            for (int i = 0; i < 64; ++i) {
#pragma unroll
                for (int q = 0; q < 4; ++q) {
                    const int row = i + 64 * q;
                    const bool rdead = (rowdead[q] >> i) & 1ull;   // wave-uniform
#pragma unroll
                    for (int j = 0; j < 4; ++j) {
                        if (cdirty & (1u << j)) {
                            float w = sc[(size_t)row * 256 + 64 * j + lane];
                            // iteration order is NOT ascending-row -> explicit tie-break
                            if (!rdead && (w > bv[j] || (w == bv[j] && row < br[j]))) {
                                bv[j] = w; br[j] = row;
                            }
                        }
                    }
                }
            }
#pragma unroll
            for (int j = 0; j < 4; ++j)
                if (cdirty & (1u << j)) { cv[j] = bv[j]; cr[j] = br[j]; }
            cdirty = 0u;
        }

        // ---- publish col caches, accept mutual pairs ----
#pragma unroll
        for (int j = 0; j < 4; ++j) lds_colarg[64 * j + lane] = cr[j];
        __syncthreads();

        unsigned acc = 0u;
#pragma unroll
        for (int j = 0; j < 4; ++j)
            if (rc[j] != SENT && lds_colarg[rc[j]] == 64 * j + lane) acc |= 1u << j;

#pragma unroll
        for (int j = 0; j < 4; ++j) {
            if (acc & (1u << j)) {
                const int r = 64 * j + lane, c = rc[j];
                ob[(size_t)r * 256 + c] = 1.0f;
                atomicOr(&lds_coldead[c >> 6], 1ull << (c & 63));
                atomicOr(&lds_rowdead[r >> 6], 1ull << (r & 63));
                rc[j] = SENT; rv[j] = NEGINF;
            }
        }
#pragma unroll
        for (int j = 0; j < 4; ++j) matched += (int)__popcll(__ballot(acc & (1u << j)));
        __syncthreads();

        // ---- refresh replicated masks; mark deaths and dirt for next round ----
        unsigned long long nrd[4], ncd[4];
#pragma unroll
        for (int w = 0; w < 4; ++w) { nrd[w] = lds_rowdead[w]; ncd[w] = lds_coldead[w]; }
#pragma unroll
        for (int j = 0; j < 4; ++j) {
            if (cr[j] != SENT) {
                const int c = 64 * j + lane;
                if ((ncd[c >> 6] >> (c & 63)) & 1ull)            { cr[j] = SENT; cv[j] = NEGINF; }
                else if ((nrd[cr[j] >> 6] >> (cr[j] & 63)) & 1ull) cdirty |= 1u << j;
            }
            if (rc[j] != SENT &&
                ((ncd[rc[j] >> 6] >> (rc[j] & 63)) & 1ull))        rdirty |= 1u << j;
        }
#pragma unroll
        for (int w = 0; w < 4; ++w) { rowdead[w] = nrd[w]; coldead[w] = ncd[w]; }
    }
}

extern "C" void kernel_launch(void* const* d_in, const int* in_sizes, int n_in,
                              void* d_out, int out_size, void* d_ws, size_t ws_size,
                              hipStream_t stream) {
    const float* soft = (const float*)d_in[0];
    float* out = (float*)d_out;
    const int n_batches = in_sizes[0] >> 16;   // elements / (256*256)
    greedy_perm_kernel<<<n_batches, 64, 0, stream>>>(soft, out);
}

// Round 5
// 424.270 us; speedup vs baseline: 2.7962x; 2.7962x over previous
//
#include <hip/hip_runtime.h>
#include <math.h>

#define NEGINF (-INFINITY)
#define C_STALE 256   // head col encoding: stale upper-bound entry
#define C_DEAD  511   // head col encoding: retired row

// One DPP max stage: x = max(x, lanes-moved(x)). old=x + bound_ctrl=false makes
// invalid source lanes contribute x (identity for max).
template <int CTRL>
__device__ __forceinline__ float dppmax(float x) {
    int xi = __float_as_int(x);
    int yi = __builtin_amdgcn_update_dpp(xi, xi, CTRL, 0xf, 0xf, false);
    return fmaxf(x, __int_as_float(yi));
}

// Wave64 max via DPP: row_shr 1/2/4/8 + row_bcast 15/31 -> lane 63, then readlane.
__device__ __forceinline__ float wave_max64(float x) {
    x = dppmax<0x111>(x);
    x = dppmax<0x112>(x);
    x = dppmax<0x114>(x);
    x = dppmax<0x118>(x);
    x = dppmax<0x142>(x);
    x = dppmax<0x143>(x);
    return __int_as_float(__builtin_amdgcn_readlane(__float_as_int(x), 63));
}

// Wave argmax over (v, idx), tie-break lowest idx.
__device__ __forceinline__ void wave_argmax(float v, int idx, float& out_v, int& out_idx) {
    float mv = wave_max64(v);
    unsigned long long mask = __ballot(v == mv);
    int ln = (int)__builtin_ctzll(mask);
    int bi = __builtin_amdgcn_readlane(idx, ln);
    unsigned long long rest = mask & (mask - 1);
    if (rest) {                      // cross-lane value ties: rare
        while (rest) {
            int l2 = (int)__builtin_ctzll(rest); rest &= rest - 1;
            int b2 = __builtin_amdgcn_readlane(idx, l2);
            if (b2 < bi) bi = b2;
        }
    }
    out_v = mv; out_idx = bi;
}

// Recompute row `row`'s head from buffered row data `b` (whole row across the
// wave: lane holds cols 4*lane..4*lane+3), masked by each lane's own colmask
// nibble. Pure VALU + DPP — no memory.
__device__ __forceinline__ void consume_row(int row, float4 b, unsigned colmask,
                                            int lane, float (&v1)[4], int (&c1)[4]) {
    float m0 = (colmask & 1u) ? NEGINF : b.x;
    float m1 = (colmask & 2u) ? NEGINF : b.y;
    float m2 = (colmask & 4u) ? NEGINF : b.z;
    float m3 = (colmask & 8u) ? NEGINF : b.w;
    float lv = m0; int lf = 4 * lane + 0;
    if (m1 > lv) { lv = m1; lf = 4 * lane + 1; }
    if (m2 > lv) { lv = m2; lf = 4 * lane + 2; }
    if (m3 > lv) { lv = m3; lf = 4 * lane + 3; }
    float rv; int rf;
    wave_argmax(lv, lf, rv, rf);     // tie-break lower col
    const int ow = row & 63, jj = row >> 6;   // jj wave-uniform
#pragma unroll
    for (int j2 = 0; j2 < 4; ++j2)
        if (j2 == jj && lane == ow) { v1[j2] = rv; c1[j2] = rf; }
}

// One wave per batch. Lane l owns rows {64j+l} (cached head value+argcol) and
// the colmask bits for cols 4l..4l+3. Rescans are one-step-deferred: row data
// prefetched into register buffers at stale time, consumed next step with the
// load latency hidden behind the intervening argmax+commit. Exactness: heads
// compare as (value, (row<<9)|col) with stale col=256 — any stale bound that
// could beat the fresh winner wins the argmax itself and forces a resolve.
__global__ __launch_bounds__(64, 1) void greedy_perm_kernel(
        const float* __restrict__ soft, float* __restrict__ out) {
    const int lane = threadIdx.x;
    const size_t base = (size_t)blockIdx.x << 16;   // b * 256 * 256
    const float* sc = soft + base;
    float* ob = out + base;

    float v1[4]; int c1[4];
#pragma unroll
    for (int j = 0; j < 4; ++j) { v1[j] = NEGINF; c1[j] = 0; }

    const float4 zero4 = make_float4(0.f, 0.f, 0.f, 0.f);

    // ---- initial per-row scans (16 loads in flight) + fused zero-fill ----
    for (int k = 0; k < 64; k += 4) {
        float4 w[4][4];
#pragma unroll
        for (int j = 0; j < 4; ++j) {
            const float4* rp = (const float4*)(sc + (size_t)(j * 64 + lane) * 256);
#pragma unroll
            for (int kk = 0; kk < 4; ++kk) w[j][kk] = rp[k + kk];
        }
#pragma unroll
        for (int j = 0; j < 4; ++j) {
            float4* op = (float4*)(ob + (size_t)(j * 64 + lane) * 256);
#pragma unroll
            for (int kk = 0; kk < 4; ++kk) op[k + kk] = zero4;
        }
#pragma unroll
        for (int j = 0; j < 4; ++j) {
#pragma unroll
            for (int kk = 0; kk < 4; ++kk) {
                const float4 ww = w[j][kk];
                const int bc = 4 * (k + kk);
                if (ww.x > v1[j]) { v1[j] = ww.x; c1[j] = bc + 0; }
                if (ww.y > v1[j]) { v1[j] = ww.y; c1[j] = bc + 1; }
                if (ww.z > v1[j]) { v1[j] = ww.z; c1[j] = bc + 2; }
                if (ww.w > v1[j]) { v1[j] = ww.w; c1[j] = bc + 3; }
            }
        }
    }
    __threadfence_block();   // zero-stores drained before any 1.0 store

    unsigned colmask = 0;                    // lane's 4 cols: taken bits
    int nstale = 0, srow0 = 0, srow1 = 0, srow2 = 0;   // wave-uniform
    float4 b0 = zero4, b1 = zero4, b2 = zero4;         // prefetched stale rows
    const int lsh = lane << 9;

    for (int step = 0; step < 256; ++step) {
        float gv; int gf;
        for (;;) {
            // local best over 4 owned rows, packed (row<<9)|col == flat order
            float bv = v1[0]; int bf = lsh | c1[0];
#pragma unroll
            for (int j = 1; j < 4; ++j) {
                int f = (j << 15) | lsh | c1[j];
                if (v1[j] > bv || (v1[j] == bv && f < bf)) { bv = v1[j]; bf = f; }
            }
            wave_argmax(bv, bf, gv, gf);
            if ((gf & 511) != C_STALE) break;   // fresh winner beats all bounds
            // a stale bound surfaced: resolve all buffers (loads long arrived)
            if (nstale >= 1) consume_row(srow0, b0, colmask, lane, v1, c1);
            if (nstale >= 2) consume_row(srow1, b1, colmask, lane, v1, c1);
            if (nstale >= 3) consume_row(srow2, b2, colmask, lane, v1, c1);
            nstale = 0;
        }
        const int r = gf >> 9, cc = gf & 511;

        if (lane == 0) ob[(size_t)r * 256 + cc] = 1.0f;
        {   // retire row r
            const int ow = r & 63, jw = r >> 6;
#pragma unroll
            for (int j2 = 0; j2 < 4; ++j2)
                if (j2 == jw && lane == ow) { v1[j2] = NEGINF; c1[j2] = C_DEAD; }
        }
        if (lane == (cc >> 2)) colmask |= 1u << (cc & 3);

        // consume previous step's prefetched rows (mask now includes cc)
        if (nstale >= 1) consume_row(srow0, b0, colmask, lane, v1, c1);
        if (nstale >= 2) consume_row(srow1, b1, colmask, lane, v1, c1);
        if (nstale >= 3) consume_row(srow2, b2, colmask, lane, v1, c1);
        nstale = 0;

        // detect new stales (heads pointing at cc), prefetch their rows
        if (step < 255) {
#pragma unroll
            for (int j = 0; j < 4; ++j) {
                unsigned long long m = __ballot(c1[j] == cc);
                while (m) {
                    const int ln = (int)__builtin_ctzll(m); m &= m - 1;
                    const int row = j * 64 + ln;
                    if (lane == ln) c1[j] = C_STALE;   // keep v1 as upper bound
                    const float4* p = (const float4*)(sc + (size_t)row * 256 + lane * 4);
                    if      (nstale == 0) { srow0 = row; b0 = *p; }
                    else if (nstale == 1) { srow1 = row; b1 = *p; }
                    else if (nstale == 2) { srow2 = row; b2 = *p; }
                    else {
                        float4 w = *p;                  // overflow: blocking (rare)
                        consume_row(row, w, colmask, lane, v1, c1);
                    }
                    ++nstale;
                }
            }
            if (nstale > 3) nstale = 3;
        }
    }
}

extern "C" void kernel_launch(void* const* d_in, const int* in_sizes, int n_in,
                              void* d_out, int out_size, void* d_ws, size_t ws_size,
                              hipStream_t stream) {
    const float* soft = (const float*)d_in[0];
    float* out = (float*)d_out;
    const int n_batches = in_sizes[0] >> 16;   // elements / (256*256)
    greedy_perm_kernel<<<n_batches, 64, 0, stream>>>(soft, out);
}

// Round 6
// 415.189 us; speedup vs baseline: 2.8574x; 1.0219x over previous
//
#include <hip/hip_runtime.h>
#include <math.h>

#define NEGINF (-INFINITY)

// ---- packed-key wave max ----------------------------------------------------
// key = (float_bits(v) << 32) | ~flat.  Softmax values are strictly > 0, so
// float order == unsigned-int order on the hi word; ~flat in the lo word makes
// u64-max tie-break to the LOWEST flat index (jnp.argmax first-occurrence).
// Dead/invalid entries are key {0,0} (any live value has hi >= 1).

template <int CTRL>
__device__ __forceinline__ void dppmax_key(unsigned& h, unsigned& l) {
    unsigned oh = (unsigned)__builtin_amdgcn_update_dpp((int)h, (int)h, CTRL, 0xf, 0xf, false);
    unsigned ol = (unsigned)__builtin_amdgcn_update_dpp((int)l, (int)l, CTRL, 0xf, 0xf, false);
    unsigned long long a = ((unsigned long long)h << 32) | l;
    unsigned long long b = ((unsigned long long)oh << 32) | ol;
    if (b > a) { h = oh; l = ol; }    // v_cmp_lt_u64 + 2 cndmask
}

// Wave64 max of packed keys -> result broadcast (readlane 63) to all lanes.
// No ballot / dynamic readlane / tie loop: index rides inside the key.
__device__ __forceinline__ void wave_max_key(unsigned& h, unsigned& l) {
    dppmax_key<0x111>(h, l);   // row_shr:1
    dppmax_key<0x112>(h, l);   // row_shr:2
    dppmax_key<0x114>(h, l);   // row_shr:4
    dppmax_key<0x118>(h, l);   // row_shr:8
    dppmax_key<0x142>(h, l);   // row_bcast:15
    dppmax_key<0x143>(h, l);   // row_bcast:31
    h = (unsigned)__builtin_amdgcn_readlane((int)h, 63);
    l = (unsigned)__builtin_amdgcn_readlane((int)l, 63);
}

__device__ __forceinline__ void take_key(unsigned& bh, unsigned& bl, unsigned h, unsigned l) {
    unsigned long long a = ((unsigned long long)bh << 32) | bl;
    unsigned long long b = ((unsigned long long)h << 32) | l;
    if (b > a) { bh = h; bl = l; }
}

// One wave per batch. Lane l owns rows {64j+l}: cached top-2 keys per row.
// Column mask kept as: per-lane nibble (cols 4l..4l+3, for rescan masking) and
// 4 wave-uniform u64 words (scalar, for promote checks).
__global__ __launch_bounds__(64, 1) void greedy_perm_kernel(
        const float* __restrict__ soft, float* __restrict__ out) {
    const int lane = threadIdx.x;
    const size_t base = (size_t)blockIdx.x << 16;   // b * 256 * 256
    const float* sc = soft + base;
    float* ob = out + base;

    unsigned k1h[4], k1l[4], k2h[4], k2l[4];

    // ---- initial per-row top-2 scans (16 loads in flight) + fused zero-fill ----
    {
        float v1[4], v2[4]; int c1[4], c2[4];
#pragma unroll
        for (int j = 0; j < 4; ++j) { v1[j] = NEGINF; c1[j] = 0; v2[j] = NEGINF; c2[j] = 0; }
        const float4 zero4 = make_float4(0.f, 0.f, 0.f, 0.f);
        for (int k = 0; k < 64; k += 4) {
            float4 w[4][4];
#pragma unroll
            for (int j = 0; j < 4; ++j) {
                const float4* rp = (const float4*)(sc + (size_t)(j * 64 + lane) * 256);
#pragma unroll
                for (int kk = 0; kk < 4; ++kk) w[j][kk] = rp[k + kk];
            }
#pragma unroll
            for (int j = 0; j < 4; ++j) {
                float4* op = (float4*)(ob + (size_t)(j * 64 + lane) * 256);
#pragma unroll
                for (int kk = 0; kk < 4; ++kk) op[k + kk] = zero4;
            }
#pragma unroll
            for (int j = 0; j < 4; ++j) {
#pragma unroll
                for (int kk = 0; kk < 4; ++kk) {
                    const float4 ww = w[j][kk];
                    const float e[4] = {ww.x, ww.y, ww.z, ww.w};
#pragma unroll
                    for (int q = 0; q < 4; ++q) {
                        const float wv = e[q];
                        const int   x  = 4 * (k + kk) + q;
                        if (wv > v1[j])      { v2[j] = v1[j]; c2[j] = c1[j]; v1[j] = wv; c1[j] = x; }
                        else if (wv > v2[j]) { v2[j] = wv; c2[j] = x; }
                    }
                }
            }
        }
#pragma unroll
        for (int j = 0; j < 4; ++j) {
            const unsigned rsh = (unsigned)((j * 64 + lane) << 8);
            k1h[j] = __float_as_uint(v1[j]); k1l[j] = ~(rsh | (unsigned)c1[j]);
            k2h[j] = __float_as_uint(v2[j]); k2l[j] = ~(rsh | (unsigned)c2[j]);
        }
    }
    __threadfence_block();   // zero-stores drained before any 1.0 store

    unsigned nib = 0;                                   // lane's 4 cols taken bits
    unsigned long long cm0 = 0, cm1 = 0, cm2 = 0, cm3 = 0;   // uniform col mask (SGPR)

    for (int step = 0; step < 256; ++step) {
        // ---- global argmax: local best of 4 keys, then wave reduce ----
        unsigned bh = k1h[0], bl = k1l[0];
        take_key(bh, bl, k1h[1], k1l[1]);
        take_key(bh, bl, k1h[2], k1l[2]);
        take_key(bh, bl, k1h[3], k1l[3]);
        wave_max_key(bh, bl);                 // -> uniform
        const unsigned flat = (~bl) & 0xFFFFu;
        const int r = (int)(flat >> 8), cc = (int)(flat & 255u);

        if (lane == 0) ob[flat] = 1.0f;

        // retire row r (uniform j branch, owner-lane predicate)
        {
            const int jw = r >> 6, ow = r & 63;
#pragma unroll
            for (int j = 0; j < 4; ++j)
                if (j == jw && lane == ow) { k1h[j] = 0; k1l[j] = 0; k2h[j] = 0; k2l[j] = 0; }
        }
        // mark column cc taken
        if (lane == (cc >> 2)) nib |= 1u << (cc & 3);
        if      (cc < 64)  cm0 |= 1ull << cc;
        else if (cc < 128) cm1 |= 1ull << (cc - 64);
        else if (cc < 192) cm2 |= 1ull << (cc - 128);
        else               cm3 |= 1ull << (cc - 192);

        if (step == 255) break;

        // ---- rows whose head col just died: promote cached #2 or rescan ----
#pragma unroll
        for (int j = 0; j < 4; ++j) {
            unsigned long long m =
                __ballot(k1h[j] != 0u && (((~k1l[j]) & 255u) == (unsigned)cc));
            while (m) {
                const int ln = (int)__builtin_ctzll(m); m &= m - 1;
                const int row = j * 64 + ln;
                const unsigned q2h = (unsigned)__builtin_amdgcn_readlane((int)k2h[j], ln);
                const unsigned q2l = (unsigned)__builtin_amdgcn_readlane((int)k2l[j], ln);
                bool promote = false;
                if (q2h != 0u) {              // cached #2 exists; col still free?
                    const int c2 = (int)((~q2l) & 255u);
                    const unsigned long long cw =
                        c2 < 64 ? cm0 : c2 < 128 ? cm1 : c2 < 192 ? cm2 : cm3;
                    promote = ((cw >> (c2 & 63)) & 1ull) == 0ull;
                }
                if (promote) {                // scalar-only fallback, no memory
                    if (lane == ln) { k1h[j] = q2h; k1l[j] = q2l; k2h[j] = 0; k2l[j] = 0; }
                } else {
                    // blocking rescan: whole row across the wave, recompute top-2
                    float4 w = *(const float4*)(sc + (size_t)row * 256 + lane * 4);
                    const unsigned lbase = ~((unsigned)(row << 8) | (unsigned)(4 * lane));
                    unsigned eh[4], el[4];
                    eh[0] = (nib & 1u) ? 0u : __float_as_uint(w.x); el[0] = lbase - 0u;
                    eh[1] = (nib & 2u) ? 0u : __float_as_uint(w.y); el[1] = lbase - 1u;
                    eh[2] = (nib & 4u) ? 0u : __float_as_uint(w.z); el[2] = lbase - 2u;
                    eh[3] = (nib & 8u) ? 0u : __float_as_uint(w.w); el[3] = lbase - 3u;
                    unsigned ah = eh[0], al = el[0];
                    take_key(ah, al, eh[1], el[1]);
                    take_key(ah, al, eh[2], el[2]);
                    take_key(ah, al, eh[3], el[3]);
                    wave_max_key(ah, al);                 // new head (uniform)
                    // mask the winner element, reduce again for the new #2
                    const int c1w = (int)((~al) & 255u), qq = c1w & 3;
#pragma unroll
                    for (int q = 0; q < 4; ++q)
                        if (q == qq && lane == (c1w >> 2)) { eh[q] = 0; el[q] = 0; }
                    unsigned sh = eh[0], sl = el[0];
                    take_key(sh, sl, eh[1], el[1]);
                    take_key(sh, sl, eh[2], el[2]);
                    take_key(sh, sl, eh[3], el[3]);
                    wave_max_key(sh, sl);                 // new #2 (uniform)
                    if (lane == ln) { k1h[j] = ah; k1l[j] = al; k2h[j] = sh; k2l[j] = sl; }
                }
            }
        }
    }
}

extern "C" void kernel_launch(void* const* d_in, const int* in_sizes, int n_in,
                              void* d_out, int out_size, void* d_ws, size_t ws_size,
                              hipStream_t stream) {
    const float* soft = (const float*)d_in[0];
    float* out = (float*)d_out;
    const int n_batches = in_sizes[0] >> 16;   // elements / (256*256)
    greedy_perm_kernel<<<n_batches, 64, 0, stream>>>(soft, out);
}

// Round 7
// 366.433 us; speedup vs baseline: 3.2375x; 1.1331x over previous
//
#include <hip/hip_runtime.h>
#include <math.h>

#define NEGINF (-INFINITY)

// ---- single-chain u32 wave max via DPP (1 v_max_u32 per stage) -------------
template <int CTRL>
__device__ __forceinline__ unsigned dppmax_u32(unsigned x) {
    unsigned y = (unsigned)__builtin_amdgcn_update_dpp((int)x, (int)x, CTRL, 0xf, 0xf, false);
    return x > y ? x : y;
}
__device__ __forceinline__ unsigned wave_max_u32(unsigned x) {
    x = dppmax_u32<0x111>(x);   // row_shr:1
    x = dppmax_u32<0x112>(x);   // row_shr:2
    x = dppmax_u32<0x114>(x);   // row_shr:4
    x = dppmax_u32<0x118>(x);   // row_shr:8
    x = dppmax_u32<0x142>(x);   // row_bcast:15
    x = dppmax_u32<0x143>(x);   // row_bcast:31
    return (unsigned)__builtin_amdgcn_readlane((int)x, 63);
}

// Exact resolution among marked lanes: each contributes (fbits, flat); winner =
// max fbits (softmax > 0 so f32 order == u32 bit order), tie -> lowest flat.
// Rare path; SALU loop over candidate lanes.
__device__ __forceinline__ unsigned resolve_exact(bool has, unsigned fbits, unsigned flat) {
    unsigned long long m = __ballot(has);
    unsigned bb = 0u, bf = 0xFFFFFFFFu;
    while (m) {
        int ln = (int)__builtin_ctzll(m); m &= m - 1;
        unsigned b2 = (unsigned)__builtin_amdgcn_readlane((int)fbits, ln);
        unsigned f2 = (unsigned)__builtin_amdgcn_readlane((int)flat, ln);
        if (b2 > bb || (b2 == bb && f2 < bf)) { bb = b2; bf = f2; }
    }
    return bf;
}

// One wave per batch. Whole matrix cached in LDS as hi16 keys (monotone for
// positive f32). Element (r,c) lives at u16 index (r<<8) + ((c + 4r) & 255)
// (row-rotate swizzle so col-kill writes spread across banks). Taken columns
// are zeroed in LDS -> rescans need no mask. Heads are u32 keys
// (hi16<<16)|~flat; picks and rescans are single-chain v_max_u32 reductions.
// hi16 ties (within-row at rescan, cross-row at pick) resolved exactly via
// f32 gather loads from global (rare).
__global__ __launch_bounds__(64, 1) void greedy_perm_kernel(
        const float* __restrict__ soft, float* __restrict__ out) {
    __shared__ unsigned short lk[65536];          // 128 KB
    const int lane = threadIdx.x;
    const size_t base = (size_t)blockIdx.x << 16;   // b * 256 * 256
    const float* sc = soft + base;
    float* ob = out + base;

    unsigned hkey[4];   // head key per owned row {64j+lane}; 0 = retired

    // ---- init: per-row max scan + hi16 LDS fill + fused zero-fill ----
    {
        float v1[4]; int c1[4];
#pragma unroll
        for (int j = 0; j < 4; ++j) { v1[j] = NEGINF; c1[j] = 0; }
        const float4 zero4 = make_float4(0.f, 0.f, 0.f, 0.f);
        for (int k = 0; k < 64; k += 4) {
            float4 w[4][4];
#pragma unroll
            for (int j = 0; j < 4; ++j) {
                const float4* rp = (const float4*)(sc + (size_t)(j * 64 + lane) * 256);
#pragma unroll
                for (int kk = 0; kk < 4; ++kk) w[j][kk] = rp[k + kk];
            }
#pragma unroll
            for (int j = 0; j < 4; ++j) {
                float4* op = (float4*)(ob + (size_t)(j * 64 + lane) * 256);
#pragma unroll
                for (int kk = 0; kk < 4; ++kk) op[k + kk] = zero4;
            }
#pragma unroll
            for (int j = 0; j < 4; ++j) {
                const int r = j * 64 + lane;
#pragma unroll
                for (int kk = 0; kk < 4; ++kk) {
                    const float4 ww = w[j][kk];
                    const int bc = 4 * (k + kk);
                    if (ww.x > v1[j]) { v1[j] = ww.x; c1[j] = bc + 0; }
                    if (ww.y > v1[j]) { v1[j] = ww.y; c1[j] = bc + 1; }
                    if (ww.z > v1[j]) { v1[j] = ww.z; c1[j] = bc + 2; }
                    if (ww.w > v1[j]) { v1[j] = ww.w; c1[j] = bc + 3; }
                    ushort4 st;
                    st.x = (unsigned short)(__float_as_uint(ww.x) >> 16);
                    st.y = (unsigned short)(__float_as_uint(ww.y) >> 16);
                    st.z = (unsigned short)(__float_as_uint(ww.z) >> 16);
                    st.w = (unsigned short)(__float_as_uint(ww.w) >> 16);
                    const int idx = (r << 8) + ((bc + (r << 2)) & 255);
                    *(ushort4*)&lk[idx] = st;
                }
            }
        }
#pragma unroll
        for (int j = 0; j < 4; ++j) {
            const unsigned flat = (unsigned)(((j * 64 + lane) << 8) | c1[j]);
            hkey[j] = ((__float_as_uint(v1[j]) >> 16) << 16) | (0xFFFFu ^ flat);
        }
    }
    __threadfence_block();   // drain zero-stores before any 1.0 store

    for (int step = 0; step < 256; ++step) {
        // ---- global pick: single u32 max over all head keys ----
        unsigned W = hkey[0];
        W = W > hkey[1] ? W : hkey[1];
        W = W > hkey[2] ? W : hkey[2];
        W = W > hkey[3] ? W : hkey[3];
        W = wave_max_u32(W);
        const unsigned k16s = W >> 16;
        unsigned flat = (~W) & 0xFFFFu;

        // cross-row hi16 tie check (winner exact iff its bucket is unique)
        {
            int cnt = (int)(hkey[0] >> 16 == k16s) + (int)(hkey[1] >> 16 == k16s)
                    + (int)(hkey[2] >> 16 == k16s) + (int)(hkey[3] >> 16 == k16s);
            unsigned long long b1 = __ballot(cnt >= 1);
            if (((b1 & (b1 - 1)) != 0ull) || __ballot(cnt >= 2)) {
                bool has = false; unsigned bb = 0u, bfl = 0xFFFFu;
#pragma unroll
                for (int j = 0; j < 4; ++j) {
                    if (hkey[j] >> 16 == k16s) {
                        const unsigned fl = (~hkey[j]) & 0xFFFFu;
                        const unsigned bits = __float_as_uint(sc[fl]);   // exact
                        if (!has || bits > bb || (bits == bb && fl < bfl)) {
                            bb = bits; bfl = fl; has = true;
                        }
                    }
                }
                flat = resolve_exact(has, bb, bfl);
            }
        }
        const int r = (int)(flat >> 8), cc = (int)(flat & 255u);

        if (lane == 0) ob[flat] = 1.0f;

        // retire row r
        {
            const int jw = r >> 6, ow = r & 63;
#pragma unroll
            for (int j = 0; j < 4; ++j)
                if (j == jw && lane == ow) hkey[j] = 0u;
        }

        // kill column cc in LDS (all 256 rows; rescans then need no mask)
#pragma unroll
        for (int j = 0; j < 4; ++j) {
            const int rr = j * 64 + lane;
            lk[(rr << 8) + ((cc + (rr << 2)) & 255)] = 0;
        }

        if (step == 255) break;

        // ---- stale heads (pointed at cc) -> LDS rescan ----
        const bool s0 = hkey[0] && (((~hkey[0]) & 255u) == (unsigned)cc);
        const bool s1 = hkey[1] && (((~hkey[1]) & 255u) == (unsigned)cc);
        const bool s2 = hkey[2] && (((~hkey[2]) & 255u) == (unsigned)cc);
        const bool s3 = hkey[3] && (((~hkey[3]) & 255u) == (unsigned)cc);
        if (__ballot(s0 | s1 | s2 | s3)) {
#pragma unroll
            for (int j = 0; j < 4; ++j) {
                const bool sj = j == 0 ? s0 : j == 1 ? s1 : j == 2 ? s2 : s3;
                unsigned long long m = __ballot(sj);
                while (m) {
                    const int ln = (int)__builtin_ctzll(m); m &= m - 1;
                    const int rp = j * 64 + ln;
                    // whole row: lane reads 4 keys (8 B) at phys offset 4*lane
                    const ushort4 kk4 = *(const ushort4*)&lk[(rp << 8) + 4 * lane];
                    const int colbase = (4 * lane - (rp << 2)) & 255;   // ≡0 mod 4
                    const unsigned flb = (unsigned)((rp << 8) | colbase);
                    unsigned ck = ((unsigned)kk4.x << 16) | (0xFFFFu ^ (flb + 0u));
                    unsigned c1k = ((unsigned)kk4.y << 16) | (0xFFFFu ^ (flb + 1u));
                    unsigned c2k = ((unsigned)kk4.z << 16) | (0xFFFFu ^ (flb + 2u));
                    unsigned c3k = ((unsigned)kk4.w << 16) | (0xFFFFu ^ (flb + 3u));
                    ck = ck > c1k ? ck : c1k;
                    ck = ck > c2k ? ck : c2k;
                    ck = ck > c3k ? ck : c3k;
                    const unsigned H = wave_max_u32(ck);
                    const unsigned k16r = H >> 16;            // >= 1 (live col exists)
                    unsigned newhead = H;
                    // within-row hi16 tie check
                    const int cnt = (int)(kk4.x == k16r) + (int)(kk4.y == k16r)
                                  + (int)(kk4.z == k16r) + (int)(kk4.w == k16r);
                    unsigned long long t1 = __ballot(cnt >= 1);
                    if (((t1 & (t1 - 1)) != 0ull) || __ballot(cnt >= 2)) {
                        bool has = false; unsigned bb = 0u, bfl = 0xFFFFu;
                        const unsigned short ks[4] = {kk4.x, kk4.y, kk4.z, kk4.w};
#pragma unroll
                        for (int q = 0; q < 4; ++q) {
                            if (ks[q] == k16r) {
                                const unsigned fl = flb + (unsigned)q;
                                const unsigned bits = __float_as_uint(sc[fl]);  // exact
                                if (!has || bits > bb || (bits == bb && fl < bfl)) {
                                    bb = bits; bfl = fl; has = true;
                                }
                            }
                        }
                        const unsigned rflat = resolve_exact(has, bb, bfl);
                        newhead = (k16r << 16) | (0xFFFFu ^ rflat);
                    }
                    if (lane == ln) {
#pragma unroll
                        for (int j2 = 0; j2 < 4; ++j2)
                            if (j2 == j) hkey[j2] = newhead;
                    }
                }
            }
        }
    }
}

extern "C" void kernel_launch(void* const* d_in, const int* in_sizes, int n_in,
                              void* d_out, int out_size, void* d_ws, size_t ws_size,
                              hipStream_t stream) {
    const float* soft = (const float*)d_in[0];
    float* out = (float*)d_out;
    const int n_batches = in_sizes[0] >> 16;   // elements / (256*256)
    greedy_perm_kernel<<<n_batches, 64, 0, stream>>>(soft, out);
}